// Round 7
// baseline (198.756 us; speedup 1.0000x reference)
//
#include <hip/hip_runtime.h>
#include <math.h>

// Problem constants (B,S,D,H,HD) = (2,2048,1024,16,64)
#define CB 2
#define CS 2048
#define CD 1024
#define CH 16
#define CHD 64
#define CM (CB*CS)   // 4096 rows

#define QSCALE 0.18033688f   // 0.125 * log2(e)
#define LOG2E  1.44269504f
#define BLOG   40.0f         // static softmax bound (log2 domain)

typedef unsigned short u16;
using bf16x8 = __attribute__((ext_vector_type(8))) short;
using u16x8  = __attribute__((ext_vector_type(8))) unsigned short;
using f32x4  = __attribute__((ext_vector_type(4))) float;

__device__ __forceinline__ u16 f2bf(float f) {
    unsigned int u = __float_as_uint(f);
    u = (u + 0x7FFFu + ((u >> 16) & 1u)) >> 16;
    return (u16)u;
}

__device__ __forceinline__ unsigned pack2bf(float a, float b) {
    unsigned ua = (__float_as_uint(a) + 0x8000u) >> 16;
    unsigned ub = (__float_as_uint(b) + 0x8000u) & 0xFFFF0000u;
    return ua | ub;
}

__device__ __forceinline__ void load_lds16(const u16* g, u16* l) {
    __builtin_amdgcn_global_load_lds(
        (const __attribute__((address_space(1))) unsigned int*)g,
        (__attribute__((address_space(3))) unsigned int*)l, 16, 0, 0);
}

// ---------------------------------------------------------------------------
__global__ __launch_bounds__(256)
void convert_x(const float* __restrict__ X, u16* __restrict__ Xb)
{
    size_t i = ((size_t)blockIdx.x * 256 + threadIdx.x) * 8;
    float4 v0 = *(const float4*)(X + i);
    float4 v1 = *(const float4*)(X + i + 4);
    u16x8 o;
    o[0] = f2bf(v0.x); o[1] = f2bf(v0.y); o[2] = f2bf(v0.z); o[3] = f2bf(v0.w);
    o[4] = f2bf(v1.x); o[5] = f2bf(v1.y); o[6] = f2bf(v1.z); o[7] = f2bf(v1.w);
    *(u16x8*)(Xb + i) = o;
}

// ---------------------------------------------------------------------------
// W [K][N] fp32 -> Wt [N][K] bf16 transposed; Wq pre-scaled by QSCALE.
// ---------------------------------------------------------------------------
__global__ __launch_bounds__(256)
void convert_wt(const float* __restrict__ Wq, const float* __restrict__ Wk,
                const float* __restrict__ Wv, u16* __restrict__ Wt)
{
    const int z = blockIdx.z;
    const float* W = (z == 0) ? Wq : (z == 1) ? Wk : Wv;
    const float sc = (z == 0) ? QSCALE : 1.0f;
    u16* Wo = Wt + (size_t)z * CD * CD;

    __shared__ u16 T[64][72];
    const int k0 = blockIdx.x << 6;
    const int n0 = blockIdx.y << 6;
    const int tid = threadIdx.x;

    #pragma unroll
    for (int it = 0; it < 4; ++it) {
        int r = (tid >> 4) + (it << 4);
        int c = (tid & 15) << 2;
        float4 v = *(const float4*)(W + (size_t)(k0 + r) * CD + n0 + c);
        T[c + 0][r] = f2bf(v.x * sc);
        T[c + 1][r] = f2bf(v.y * sc);
        T[c + 2][r] = f2bf(v.z * sc);
        T[c + 3][r] = f2bf(v.w * sc);
    }
    __syncthreads();
    #pragma unroll
    for (int it = 0; it < 2; ++it) {
        int cc = tid + (it << 8);
        int n  = cc >> 3;
        int ch = (cc & 7) << 3;
        *(uint4*)(Wo + (size_t)(n0 + n) * CD + k0 + ch) = *(const uint4*)&T[n][ch];
    }
}

// ---------------------------------------------------------------------------
// QKV GEMM v3: 128x64 tile (M x N), BK=64, 6 blocks/CU (24 waves) for latency
// hiding.  Wave-tile 64x32 (mi=4, nt=2), acc = 32 VGPR.  global_load_lds
// staging with 8-slot XOR swizzle (slot = chunk ^ (row&7)); fragment
// ds_read_b128 at slot (kk*4+quad)^(l15&7) is 2-way (free).
// Grid (N/64, M/128, 3); x-fastest keeps one A-panel per 16 consecutive
// blocks (L2 locality).  Single-phase LDS epilogues (full C-tile fits 24 KB).
// ---------------------------------------------------------------------------
__global__ __launch_bounds__(256, 6)
void qkv_gemm_mfma(const u16* __restrict__ Xb, const u16* __restrict__ Wt,
                   const float* __restrict__ bq, const float* __restrict__ bk,
                   const float* __restrict__ bv,
                   u16* __restrict__ Qb, u16* __restrict__ Kb,
                   u16* __restrict__ Vt)
{
    const int z = blockIdx.z;
    const u16* W = Wt + (size_t)z * CD * CD;
    const float* bias = (z == 0) ? bq : (z == 1) ? bk : bv;
    const float bscale = (z == 0) ? QSCALE : 1.0f;

    __shared__ u16 smem[12288];         // As [128][64] 16KB + Bs [64][64] 8KB
    u16* As = smem;
    u16* Bs = smem + 8192;

    const int tid  = threadIdx.x;
    const int w    = tid >> 6;
    const int l    = tid & 63;
    const int l15  = l & 15;
    const int quad = l >> 4;
    const int wm   = w >> 1;            // 0..1: 64-row half
    const int wn   = w & 1;             // 0..1: 32-col half

    const int n0   = blockIdx.x << 6;   // 64-wide col tile == one head
    const int row0 = blockIdx.y << 7;

    f32x4 acc[4][2];
    #pragma unroll
    for (int mi = 0; mi < 4; ++mi)
        #pragma unroll
        for (int nt = 0; nt < 2; ++nt)
            acc[mi][nt] = (f32x4){0.f, 0.f, 0.f, 0.f};

    const u16* Ag = Xb + (size_t)row0 * CD;
    const u16* Bg = W  + (size_t)n0   * CD;
    const int lr8 = l >> 3;                 // row within 8-row group
    const int lg  = ((l & 7) ^ lr8) << 3;   // swizzled chunk offset (u16)
    const int q7  = l15 & 7;

    for (int k0 = 0; k0 < CD; k0 += 64) {
        __syncthreads();
        #pragma unroll
        for (int i = 0; i < 4; ++i) {
            int r = w * 32 + 8 * i;
            load_lds16(Ag + (size_t)(r + lr8) * CD + k0 + lg, As + (size_t)r * 64);
        }
        #pragma unroll
        for (int i = 0; i < 2; ++i) {
            int r = w * 16 + 8 * i;
            load_lds16(Bg + (size_t)(r + lr8) * CD + k0 + lg, Bs + (size_t)r * 64);
        }
        __syncthreads();

        #pragma unroll
        for (int kk = 0; kk < 2; ++kk) {
            const int slot = ((kk * 4 + quad) ^ q7) << 3;
            bf16x8 af[4], bfr[2];
            #pragma unroll
            for (int mi = 0; mi < 4; ++mi)
                af[mi] = *(const bf16x8*)&As[(wm * 64 + mi * 16 + l15) * 64 + slot];
            #pragma unroll
            for (int nt = 0; nt < 2; ++nt)
                bfr[nt] = *(const bf16x8*)&Bs[(wn * 32 + nt * 16 + l15) * 64 + slot];
            #pragma unroll
            for (int mi = 0; mi < 4; ++mi)
                #pragma unroll
                for (int nt = 0; nt < 2; ++nt)
                    acc[mi][nt] = __builtin_amdgcn_mfma_f32_16x16x32_bf16(
                        af[mi], bfr[nt], acc[mi][nt], 0, 0, 0);
        }
    }

    __syncthreads();   // K-loop LDS reads done; smem reusable
    const int h = n0 >> 6;

    if (z < 2) {
        u16* Og = (z == 0) ? Qb : Kb;
        float bb[2];
        #pragma unroll
        for (int nt = 0; nt < 2; ++nt)
            bb[nt] = bias[n0 + wn * 32 + nt * 16 + l15] * bscale;

        u16 (*Ct)[72] = (u16(*)[72])smem;   // [m 0..127][n 0..63]
        #pragma unroll
        for (int nt = 0; nt < 2; ++nt)
            #pragma unroll
            for (int mi = 0; mi < 4; ++mi)
                #pragma unroll
                for (int r = 0; r < 4; ++r)
                    Ct[wm * 64 + mi * 16 + quad * 4 + r][wn * 32 + nt * 16 + l15] =
                        f2bf(acc[mi][nt][r] + bb[nt]);
        __syncthreads();
        #pragma unroll
        for (int it = 0; it < 4; ++it) {
            int c  = tid + (it << 8);
            int rl = c >> 3;          // 0..127
            int ck = c & 7;           // 8-col chunk
            uint4 d = *(const uint4*)&Ct[rl][ck * 8];
            int m = row0 + rl;
            int b = m >> 11, s = m & (CS - 1);
            *(uint4*)(Og + ((size_t)(b * CH + h) * CS + s) * CHD + ck * 8) = d;
        }
    } else {
        // V: transpose -> [b,h,hd,s]
        u16 (*Ct)[136] = (u16(*)[136])smem;   // [dv 0..63][m 0..127]
        #pragma unroll
        for (int nt = 0; nt < 2; ++nt) {
            float bb = bias[n0 + wn * 32 + nt * 16 + l15];
            #pragma unroll
            for (int mi = 0; mi < 4; ++mi)
                #pragma unroll
                for (int r = 0; r < 4; ++r)
                    Ct[wn * 32 + nt * 16 + l15][wm * 64 + mi * 16 + quad * 4 + r] =
                        f2bf(acc[mi][nt][r] + bb);
        }
        __syncthreads();
        #pragma unroll
        for (int it = 0; it < 4; ++it) {
            int c   = tid + (it << 8);
            int dvl = c >> 4;         // 0..63
            int ch  = c & 15;         // 8-row chunk
            uint4 vdat = *(const uint4*)&Ct[dvl][ch * 8];
            int m0 = row0 + ch * 8;
            int b  = m0 >> 11;
            int s0 = m0 & (CS - 1);
            *(uint4*)(Vt + (((size_t)(b * CH + h)) * CHD + dvl) * CS + s0) = vdat;
        }
    }
}

// ---------------------------------------------------------------------------
// Flash attention v7: q-block 64 -> grid 1024 blocks = 4 blocks/CU (16 waves)
// for latency hiding.  LDS exactly 32 KB: msk 8K + single-buffered Kst 8K +
// Vst 8K + per-wave P 8K.  2 barriers/tile; cross-block wave overlap covers
// the DMA drain (m114).  Static-bound softmax in exp2 domain; C-init = mask;
// P via wave-private XOR-swizzled LDS; l reduced with 2 shfls + 4-shfl bcast.
// ---------------------------------------------------------------------------
__global__ __launch_bounds__(256, 4)
void attn_mfma(const u16* __restrict__ Qg, const u16* __restrict__ Kg,
               const u16* __restrict__ Vtg, const float* __restrict__ mask,
               float* __restrict__ out)
{
    __shared__ float msk[CS];           // 8 KB: mask*log2e - B
    __shared__ u16   Kst[64 * 64];      // 8 KB: K tile [key][d], swizzled
    __shared__ u16   Vst[64 * 64];      // 8 KB: V^T tile [dv][key], swizzled
    __shared__ u16   Pl[4][16 * 64];    // 8 KB: per-wave P (16 q x 64 k)

    const int q0  = blockIdx.x << 6;
    const int bh  = blockIdx.y;
    const int b   = bh >> 4;
    const int h   = bh & 15;
    const int tid = threadIdx.x;
    const int w    = tid >> 6;
    const int l    = tid & 63;
    const int l15  = l & 15;
    const int quad = l >> 4;
    const int q7   = l15 & 7;
    const int lr8  = l >> 3;
    const int lg   = ((l & 7) ^ lr8) << 3;

    const u16* Qp = Qg  + (size_t)bh * CS * CHD;
    const u16* Kp = Kg  + (size_t)bh * CS * CHD;
    const u16* Vp = Vtg + (size_t)bh * CHD * CS;
    const float* mrow = mask + (size_t)b * CS;

    // stage mask (log2 domain, static bound folded in)
    {
        int i = tid * 8;
        float4 a = *(const float4*)(mrow + i);
        float4 c = *(const float4*)(mrow + i + 4);
        msk[i + 0] = a.x * LOG2E - BLOG; msk[i + 1] = a.y * LOG2E - BLOG;
        msk[i + 2] = a.z * LOG2E - BLOG; msk[i + 3] = a.w * LOG2E - BLOG;
        msk[i + 4] = c.x * LOG2E - BLOG; msk[i + 5] = c.y * LOG2E - BLOG;
        msk[i + 6] = c.z * LOG2E - BLOG; msk[i + 7] = c.w * LOG2E - BLOG;
    }

    // Q B-fragments in registers for the whole loop (wave w owns 16 q rows)
    bf16x8 qf[2];
    #pragma unroll
    for (int hh = 0; hh < 2; ++hh)
        qf[hh] = *(const bf16x8*)(
            Qp + (size_t)(q0 + w * 16 + l15) * CHD + hh * 32 + quad * 8);

    u16* Pw = &Pl[w][0];
    float lsum = 0.f;
    f32x4 O[4];
    #pragma unroll
    for (int dt = 0; dt < 4; ++dt) O[dt] = (f32x4){0.f, 0.f, 0.f, 0.f};

    for (int kt = 0; kt < CS / 64; ++kt) {
        const int k0 = kt << 6;
        __syncthreads();                 // prev tile reads done (kt=0: msk fence)
        #pragma unroll
        for (int i = 0; i < 2; ++i) {
            int rl = w * 16 + 8 * i;
            load_lds16(Kp + (size_t)(k0 + rl + lr8) * CHD + lg, &Kst[rl * 64]);
            load_lds16(Vp + (size_t)(rl + lr8) * CS + k0 + lg,  &Vst[rl * 64]);
        }
        __syncthreads();                 // DMA complete across all waves

        // K A-fragments
        bf16x8 kf[4][2];
        #pragma unroll
        for (int mt = 0; mt < 4; ++mt)
            #pragma unroll
            for (int hh = 0; hh < 2; ++hh)
                kf[mt][hh] = *(const bf16x8*)
                    &Kst[(mt * 16 + l15) * 64 + (((hh * 4 + quad) ^ q7) << 3)];

        // S^T = K.Q^T, C-init = mask
        f32x4 st[4];
        #pragma unroll
        for (int mt = 0; mt < 4; ++mt) {
            f32x4 c0 = *(const f32x4*)&msk[k0 + mt * 16 + quad * 4];
            c0 = __builtin_amdgcn_mfma_f32_16x16x32_bf16(kf[mt][0], qf[0], c0, 0, 0, 0);
            st[mt] = __builtin_amdgcn_mfma_f32_16x16x32_bf16(kf[mt][1], qf[1], c0, 0, 0, 0);
        }

        // exp2 + sum + pack -> wave-private P
        float rs = lsum;
        #pragma unroll
        for (int mt = 0; mt < 4; ++mt) {
            #pragma unroll
            for (int r = 0; r < 4; ++r) {
                st[mt][r] = exp2f(st[mt][r]);
                rs += st[mt][r];
            }
            int g = 2 * mt + (quad >> 1);
            int addr = l15 * 64 + ((g ^ q7) << 3) + ((quad & 1) << 2);
            uint2 d;
            d.x = pack2bf(st[mt][0], st[mt][1]);
            d.y = pack2bf(st[mt][2], st[mt][3]);
            *(uint2*)&Pw[addr] = d;
        }
        lsum = rs;

        // P A-fragments back (wave-private, no barrier)
        bf16x8 pf[2];
        #pragma unroll
        for (int hh = 0; hh < 2; ++hh)
            pf[hh] = *(const bf16x8*)
                &Pw[l15 * 64 + (((hh * 4 + quad) ^ q7) << 3)];

        // V^T B-fragments
        bf16x8 vf[4][2];
        #pragma unroll
        for (int dt = 0; dt < 4; ++dt)
            #pragma unroll
            for (int hh = 0; hh < 2; ++hh)
                vf[dt][hh] = *(const bf16x8*)
                    &Vst[(dt * 16 + l15) * 64 + (((hh * 4 + quad) ^ q7) << 3)];

        // O += P.V  (no rescale: static bound)
        #pragma unroll
        for (int dt = 0; dt < 4; ++dt) {
            O[dt] = __builtin_amdgcn_mfma_f32_16x16x32_bf16(pf[0], vf[dt][0], O[dt], 0, 0, 0);
            O[dt] = __builtin_amdgcn_mfma_f32_16x16x32_bf16(pf[1], vf[dt][1], O[dt], 0, 0, 0);
        }
    }

    // l reduce across quads; all lanes j<16 then hold l(q-local=j)
    lsum += __shfl_xor(lsum, 16);
    lsum += __shfl_xor(lsum, 32);

    #pragma unroll
    for (int r = 0; r < 4; ++r) {
        float inv = 1.0f / __shfl(lsum, quad * 4 + r);
        int q = q0 + w * 16 + quad * 4 + r;
        float* orow = out + ((size_t)b * CS + q) * CD + h * CHD;
        #pragma unroll
        for (int dt = 0; dt < 4; ++dt)
            orow[dt * 16 + l15] = O[dt][r] * inv;
    }
}

// ---------------------------------------------------------------------------
extern "C" void kernel_launch(void* const* d_in, const int* in_sizes, int n_in,
                              void* d_out, int out_size, void* d_ws, size_t ws_size,
                              hipStream_t stream)
{
    const float* X    = (const float*)d_in[0];
    const float* mask = (const float*)d_in[1];
    const float* Wq   = (const float*)d_in[2];
    const float* bq   = (const float*)d_in[3];
    const float* Wk   = (const float*)d_in[4];
    const float* bk   = (const float*)d_in[5];
    const float* Wv   = (const float*)d_in[6];
    const float* bv   = (const float*)d_in[7];
    float* out = (float*)d_out;

    char* ws = (char*)d_ws;
    u16* Xb = (u16*)(ws);
    u16* Wt = (u16*)(ws + ((size_t)8  << 20));
    u16* Qb = (u16*)(ws + ((size_t)14 << 20));
    u16* Kb = (u16*)(ws + ((size_t)22 << 20));
    u16* Vt = (u16*)(ws + ((size_t)30 << 20));

    convert_x<<<CM * CD / (256 * 8), 256, 0, stream>>>(X, Xb);
    convert_wt<<<dim3(16, 16, 3), 256, 0, stream>>>(Wq, Wk, Wv, Wt);
    qkv_gemm_mfma<<<dim3(CD / 64, CM / 128, 3), 256, 0, stream>>>(
        Xb, Wt, bq, bk, bv, Qb, Kb, Vt);
    attn_mfma<<<dim3(CS / 64, CB * CH), 256, 0, stream>>>(Qb, Kb, Vt, mask, out);
}

// Round 8
// 190.617 us; speedup vs baseline: 1.0427x; 1.0427x over previous
//
#include <hip/hip_runtime.h>
#include <math.h>

// Problem constants (B,S,D,H,HD) = (2,2048,1024,16,64)
#define CB 2
#define CS 2048
#define CD 1024
#define CH 16
#define CHD 64
#define CM (CB*CS)   // 4096 rows

#define QSCALE 0.18033688f   // 0.125 * log2(e)
#define LOG2E  1.44269504f
#define BLOG   40.0f         // static softmax bound (log2 domain)

typedef unsigned short u16;
using bf16x8 = __attribute__((ext_vector_type(8))) short;
using u16x8  = __attribute__((ext_vector_type(8))) unsigned short;
using f32x4  = __attribute__((ext_vector_type(4))) float;

__device__ __forceinline__ u16 f2bf(float f) {
    unsigned int u = __float_as_uint(f);
    u = (u + 0x7FFFu + ((u >> 16) & 1u)) >> 16;
    return (u16)u;
}

__device__ __forceinline__ unsigned pack2bf(float a, float b) {
    unsigned ua = (__float_as_uint(a) + 0x8000u) >> 16;
    unsigned ub = (__float_as_uint(b) + 0x8000u) & 0xFFFF0000u;
    return ua | ub;
}

__device__ __forceinline__ void load_lds16(const u16* g, u16* l) {
    __builtin_amdgcn_global_load_lds(
        (const __attribute__((address_space(1))) unsigned int*)g,
        (__attribute__((address_space(3))) unsigned int*)l, 16, 0, 0);
}

// ---------------------------------------------------------------------------
__global__ __launch_bounds__(256)
void convert_x(const float* __restrict__ X, u16* __restrict__ Xb)
{
    size_t i = ((size_t)blockIdx.x * 256 + threadIdx.x) * 8;
    float4 v0 = *(const float4*)(X + i);
    float4 v1 = *(const float4*)(X + i + 4);
    u16x8 o;
    o[0] = f2bf(v0.x); o[1] = f2bf(v0.y); o[2] = f2bf(v0.z); o[3] = f2bf(v0.w);
    o[4] = f2bf(v1.x); o[5] = f2bf(v1.y); o[6] = f2bf(v1.z); o[7] = f2bf(v1.w);
    *(u16x8*)(Xb + i) = o;
}

// ---------------------------------------------------------------------------
// W [K][N] fp32 -> Wt [N][K] bf16 transposed; Wq pre-scaled by QSCALE.
// ---------------------------------------------------------------------------
__global__ __launch_bounds__(256)
void convert_wt(const float* __restrict__ Wq, const float* __restrict__ Wk,
                const float* __restrict__ Wv, u16* __restrict__ Wt)
{
    const int z = blockIdx.z;
    const float* W = (z == 0) ? Wq : (z == 1) ? Wk : Wv;
    const float sc = (z == 0) ? QSCALE : 1.0f;
    u16* Wo = Wt + (size_t)z * CD * CD;

    __shared__ u16 T[64][72];
    const int k0 = blockIdx.x << 6;
    const int n0 = blockIdx.y << 6;
    const int tid = threadIdx.x;

    #pragma unroll
    for (int it = 0; it < 4; ++it) {
        int r = (tid >> 4) + (it << 4);
        int c = (tid & 15) << 2;
        float4 v = *(const float4*)(W + (size_t)(k0 + r) * CD + n0 + c);
        T[c + 0][r] = f2bf(v.x * sc);
        T[c + 1][r] = f2bf(v.y * sc);
        T[c + 2][r] = f2bf(v.z * sc);
        T[c + 3][r] = f2bf(v.w * sc);
    }
    __syncthreads();
    #pragma unroll
    for (int it = 0; it < 2; ++it) {
        int cc = tid + (it << 8);
        int n  = cc >> 3;
        int ch = (cc & 7) << 3;
        *(uint4*)(Wo + (size_t)(n0 + n) * CD + k0 + ch) = *(const uint4*)&T[n][ch];
    }
}

// ---------------------------------------------------------------------------
// QKV GEMM (R6 form — best measured): bf16 MFMA 16x16x32, 128x128 tile,
// BK=64, global_load_lds staging with 8-slot XOR swizzle; fragment
// ds_read_b128 at slot (kk*4+quad)^(l15&7) is 2-way (free).  3 blocks/CU.
// z=0/1 -> Q/K bf16 [b,h,s,hd]; z=2 -> V bf16 transposed [b,h,hd,s].
// ---------------------------------------------------------------------------
__global__ __launch_bounds__(256, 3)
void qkv_gemm_mfma(const u16* __restrict__ Xb, const u16* __restrict__ Wt,
                   const float* __restrict__ bq, const float* __restrict__ bk,
                   const float* __restrict__ bv,
                   u16* __restrict__ Qb, u16* __restrict__ Kb,
                   u16* __restrict__ Vt)
{
    const int z = blockIdx.z;
    const u16* W = Wt + (size_t)z * CD * CD;
    const float* bias = (z == 0) ? bq : (z == 1) ? bk : bv;
    const float bscale = (z == 0) ? QSCALE : 1.0f;

    __shared__ u16 smem[16384];         // As [128][64] + Bs [128][64] = 32 KB
    u16* As = smem;
    u16* Bs = smem + 8192;

    const int tid  = threadIdx.x;
    const int w    = tid >> 6;
    const int l    = tid & 63;
    const int l15  = l & 15;
    const int quad = l >> 4;
    const int wm   = w >> 1;
    const int wn   = w & 1;

    const int row0 = blockIdx.x << 7;
    const int n0   = blockIdx.y << 7;

    f32x4 acc[4][4];
    #pragma unroll
    for (int mi = 0; mi < 4; ++mi)
        #pragma unroll
        for (int nt = 0; nt < 4; ++nt)
            acc[mi][nt] = (f32x4){0.f, 0.f, 0.f, 0.f};

    const u16* Ag = Xb + (size_t)row0 * CD;
    const u16* Bg = W  + (size_t)n0   * CD;
    const int lr8 = l >> 3;                 // row within 8-row group
    const int ls  = l & 7;                  // stored slot
    const int lg  = (ls ^ lr8) << 3;        // swizzled global chunk (u16)
    const int q7  = l15 & 7;

    for (int k0 = 0; k0 < CD; k0 += 64) {
        __syncthreads();
        #pragma unroll
        for (int i = 0; i < 4; ++i) {
            int r = w * 32 + 8 * i + lr8;
            load_lds16(Ag + (size_t)r * CD + k0 + lg, As + (size_t)(w * 32 + 8 * i) * 64);
            load_lds16(Bg + (size_t)r * CD + k0 + lg, Bs + (size_t)(w * 32 + 8 * i) * 64);
        }
        __syncthreads();

        #pragma unroll
        for (int kk = 0; kk < 2; ++kk) {
            bf16x8 af[4], bfr[4];
            #pragma unroll
            for (int mi = 0; mi < 4; ++mi)
                af[mi] = *(const bf16x8*)
                    &As[(wm * 64 + mi * 16 + l15) * 64 + (((kk * 4 + quad) ^ q7) << 3)];
            #pragma unroll
            for (int nt = 0; nt < 4; ++nt)
                bfr[nt] = *(const bf16x8*)
                    &Bs[(wn * 64 + nt * 16 + l15) * 64 + (((kk * 4 + quad) ^ q7) << 3)];
            #pragma unroll
            for (int mi = 0; mi < 4; ++mi)
                #pragma unroll
                for (int nt = 0; nt < 4; ++nt)
                    acc[mi][nt] = __builtin_amdgcn_mfma_f32_16x16x32_bf16(
                        af[mi], bfr[nt], acc[mi][nt], 0, 0, 0);
        }
    }

    __syncthreads();   // K-loop LDS reads done; smem reusable

    if (z < 2) {
        u16* Og = (z == 0) ? Qb : Kb;
        float bb[4];
        #pragma unroll
        for (int nt = 0; nt < 4; ++nt)
            bb[nt] = bias[n0 + wn * 64 + nt * 16 + l15] * bscale;

        u16 (*Ct)[136] = (u16(*)[136])smem;
        #pragma unroll
        for (int mh = 0; mh < 2; ++mh) {
            if (wm == mh) {
                #pragma unroll
                for (int nt = 0; nt < 4; ++nt)
                    #pragma unroll
                    for (int mi = 0; mi < 4; ++mi)
                        #pragma unroll
                        for (int r = 0; r < 4; ++r)
                            Ct[mi * 16 + quad * 4 + r][wn * 64 + nt * 16 + l15] =
                                f2bf(acc[mi][nt][r] + bb[nt]);
            }
            __syncthreads();
            #pragma unroll
            for (int it = 0; it < 4; ++it) {
                int c  = tid + (it << 8);
                int rl = c >> 4;
                int ck = c & 15;
                uint4 d = *(const uint4*)&Ct[rl][ck * 8];
                int gcol = n0 + ck * 8;
                int h = gcol >> 6, hd = gcol & 63;
                int m = row0 + mh * 64 + rl;
                int b = m >> 11, s = m & (CS - 1);
                *(uint4*)(Og + ((size_t)(b * CH + h) * CS + s) * CHD + hd) = d;
            }
            __syncthreads();
        }
    } else {
        u16 (*Ct)[136] = (u16(*)[136])smem;
        #pragma unroll
        for (int nh = 0; nh < 2; ++nh) {
            if (wn == nh) {
                #pragma unroll
                for (int nt = 0; nt < 4; ++nt) {
                    int col = n0 + nh * 64 + nt * 16 + l15;
                    float bb = bias[col];
                    #pragma unroll
                    for (int mi = 0; mi < 4; ++mi)
                        #pragma unroll
                        for (int r = 0; r < 4; ++r) {
                            int ml = wm * 64 + mi * 16 + quad * 4 + r;
                            Ct[nt * 16 + l15][ml] = f2bf(acc[mi][nt][r] + bb);
                        }
                }
            }
            __syncthreads();
            #pragma unroll
            for (int it = 0; it < 4; ++it) {
                int c   = tid + (it << 8);
                int dvl = c >> 4;
                int ch  = c & 15;
                uint4 vdat = *(const uint4*)&Ct[dvl][ch * 8];
                int col = n0 + nh * 64 + dvl;
                int h   = col >> 6;
                int dv  = col & 63;
                int m0  = row0 + ch * 8;
                int b   = m0 >> 11;
                int s0  = m0 & (CS - 1);
                *(uint4*)(Vt + (((size_t)(b * CH + h)) * CHD + dv) * CS + s0) = vdat;
            }
            __syncthreads();
        }
    }
}

// ---------------------------------------------------------------------------
// Flash attention v8: 512-thread blocks (8 waves), in-block k-split.
// Wave w: q-group qh=w&3 (32 q, nq=2), key-half kh=w>>2 (1024 keys, 16 tiles).
// Grid (S/128, B*H) = 512 blocks -> 2 blocks/CU x 8 waves = 16 waves/CU with
// the nq=2 LDS traffic profile (floor ~36 us).  LDS exactly 64 KB:
// Kst[2] 16K + Vst[2] 16K + P[8] 32K; mask read from global per tile
// (fma * LOG2E - BLOG); combine buffers overlay dead K/V/P after the loop.
// Static-bound softmax (linear partials) -> k-halves combine additively.
// ---------------------------------------------------------------------------
__global__ __launch_bounds__(512, 4)
void attn_mfma(const u16* __restrict__ Qg, const u16* __restrict__ Kg,
               const u16* __restrict__ Vtg, const float* __restrict__ mask,
               float* __restrict__ out)
{
    __shared__ u16 smem[32768];         // 64 KB
    u16* KstB = smem;                   // [2][64*64]  K tiles per half
    u16* VstB = smem + 8192;            // [2][64*64]  V^T tiles per half
    u16* PlB  = smem + 16384;           // [8][32*64]  per-wave P

    const int q0  = blockIdx.x << 7;
    const int bh  = blockIdx.y;
    const int b   = bh >> 4;
    const int h   = bh & 15;
    const int tid = threadIdx.x;
    const int w    = tid >> 6;          // 0..7
    const int qh   = w & 3;             // q-group (32 q)
    const int kh   = w >> 2;            // key half
    const int l    = tid & 63;
    const int l15  = l & 15;
    const int quad = l >> 4;
    const int q7   = l15 & 7;
    const int lr8  = l >> 3;
    const int lg   = ((l & 7) ^ lr8) << 3;

    const u16* Qp     = Qg  + (size_t)bh * CS * CHD;
    const u16* Kph    = Kg  + (size_t)bh * CS * CHD + ((size_t)(kh << 10)) * CHD;
    const u16* Vph    = Vtg + (size_t)bh * CHD * CS + (kh << 10);
    const float* mrh  = mask + (size_t)b * CS + (kh << 10);

    u16* Kst = KstB + kh * 4096;
    u16* Vst = VstB + kh * 4096;
    u16* Pw  = PlB  + w * 2048;

    // Q B-fragments in registers: q = q0 + qh*32 + nq*16 + l15
    bf16x8 qf[2][2];
    #pragma unroll
    for (int nq = 0; nq < 2; ++nq)
        #pragma unroll
        for (int hh = 0; hh < 2; ++hh)
            qf[nq][hh] = *(const bf16x8*)(
                Qp + (size_t)(q0 + qh * 32 + nq * 16 + l15) * CHD + hh * 32 + quad * 8);

    float lsum[2] = {0.f, 0.f};
    f32x4 O[2][4];
    #pragma unroll
    for (int nq = 0; nq < 2; ++nq)
        #pragma unroll
        for (int dt = 0; dt < 4; ++dt)
            O[nq][dt] = (f32x4){0.f, 0.f, 0.f, 0.f};

    for (int kt = 0; kt < 16; ++kt) {
        const int k0 = kt << 6;
        __syncthreads();                 // prev tile reads done
        // stage: 4 waves of each half cover 64 K rows + 64 V^T rows
        #pragma unroll
        for (int i = 0; i < 2; ++i) {
            int rl = qh * 16 + 8 * i;
            load_lds16(Kph + (size_t)(k0 + rl + lr8) * CHD + lg, &Kst[rl * 64]);
            load_lds16(Vph + (size_t)(rl + lr8) * CS + k0 + lg,  &Vst[rl * 64]);
        }
        __syncthreads();                 // DMA complete across all waves

        // K A-fragments (swizzled, 2-way)
        bf16x8 kf[4][2];
        #pragma unroll
        for (int mt = 0; mt < 4; ++mt)
            #pragma unroll
            for (int hh = 0; hh < 2; ++hh)
                kf[mt][hh] = *(const bf16x8*)
                    &Kst[(mt * 16 + l15) * 64 + (((hh * 4 + quad) ^ q7) << 3)];

        // mask -> C-init (log2 domain, static bound folded)
        f32x4 mc[4];
        #pragma unroll
        for (int mt = 0; mt < 4; ++mt) {
            f32x4 mv = *(const f32x4*)(mrh + k0 + mt * 16 + quad * 4);
            #pragma unroll
            for (int r = 0; r < 4; ++r)
                mc[mt][r] = fmaf(mv[r], LOG2E, -BLOG);
        }

        // S^T + exp2 + pack (nq-sequenced to bound register pressure)
        #pragma unroll
        for (int nq = 0; nq < 2; ++nq) {
            f32x4 st[4];
            #pragma unroll
            for (int mt = 0; mt < 4; ++mt) {
                f32x4 c0 = mc[mt];
                c0 = __builtin_amdgcn_mfma_f32_16x16x32_bf16(kf[mt][0], qf[nq][0], c0, 0, 0, 0);
                st[mt] = __builtin_amdgcn_mfma_f32_16x16x32_bf16(kf[mt][1], qf[nq][1], c0, 0, 0, 0);
            }
            float rs = lsum[nq];
            #pragma unroll
            for (int mt = 0; mt < 4; ++mt) {
                #pragma unroll
                for (int r = 0; r < 4; ++r) {
                    st[mt][r] = exp2f(st[mt][r]);
                    rs += st[mt][r];
                }
                int g = 2 * mt + (quad >> 1);
                int addr = (nq * 16 + l15) * 64 + ((g ^ q7) << 3) + ((quad & 1) << 2);
                uint2 d;
                d.x = pack2bf(st[mt][0], st[mt][1]);
                d.y = pack2bf(st[mt][2], st[mt][3]);
                *(uint2*)&Pw[addr] = d;
            }
            lsum[nq] = rs;
        }

        // P A-fragments back (wave-private, no barrier)
        bf16x8 pf[2][2];
        #pragma unroll
        for (int nq = 0; nq < 2; ++nq)
            #pragma unroll
            for (int hh = 0; hh < 2; ++hh)
                pf[nq][hh] = *(const bf16x8*)
                    &Pw[(nq * 16 + l15) * 64 + (((hh * 4 + quad) ^ q7) << 3)];

        // V^T B-fragments
        bf16x8 vf[4][2];
        #pragma unroll
        for (int dt = 0; dt < 4; ++dt)
            #pragma unroll
            for (int hh = 0; hh < 2; ++hh)
                vf[dt][hh] = *(const bf16x8*)
                    &Vst[(dt * 16 + l15) * 64 + (((hh * 4 + quad) ^ q7) << 3)];

        // O += P.V  (no rescale: static bound)
        #pragma unroll
        for (int nq = 0; nq < 2; ++nq)
            #pragma unroll
            for (int dt = 0; dt < 4; ++dt) {
                O[nq][dt] = __builtin_amdgcn_mfma_f32_16x16x32_bf16(
                    pf[nq][0], vf[dt][0], O[nq][dt], 0, 0, 0);
                O[nq][dt] = __builtin_amdgcn_mfma_f32_16x16x32_bf16(
                    pf[nq][1], vf[dt][1], O[nq][dt], 0, 0, 0);
            }
    }

    // ---- combine k-halves (linear: static bound) ----
    #pragma unroll
    for (int nq = 0; nq < 2; ++nq) {
        lsum[nq] += __shfl_xor(lsum[nq], 16);
        lsum[nq] += __shfl_xor(lsum[nq], 32);
    }

    __syncthreads();   // all LDS reads of last tile done; smem reusable
    float* ob   = (float*)smem;          // 32 KB: 4 pairs x 32 q x 64 dv fp32
    float* lbuf = (float*)PlB;           // 128 floats (P region dead)

    if (kh == 1) {
        float* obw = ob + qh * 2048;
        #pragma unroll
        for (int nq = 0; nq < 2; ++nq)
            #pragma unroll
            for (int dt = 0; dt < 4; ++dt)
                #pragma unroll
                for (int r = 0; r < 4; ++r)
                    obw[(nq * 16 + quad * 4 + r) * 64 + dt * 16 + l15] = O[nq][dt][r];
        if (quad == 0) {
            lbuf[qh * 32 + l15]      = lsum[0];
            lbuf[qh * 32 + 16 + l15] = lsum[1];
        }
    }
    __syncthreads();

    if (kh == 0) {
        const float* obw = ob + qh * 2048;
        #pragma unroll
        for (int nq = 0; nq < 2; ++nq) {
            float inv = 1.0f / (lsum[nq] + lbuf[qh * 32 + nq * 16 + l15]);
            #pragma unroll
            for (int r = 0; r < 4; ++r) {
                float invr = __shfl(inv, quad * 4 + r);
                int q = q0 + qh * 32 + nq * 16 + quad * 4 + r;
                float* orow = out + ((size_t)b * CS + q) * CD + h * CHD;
                #pragma unroll
                for (int dt = 0; dt < 4; ++dt)
                    orow[dt * 16 + l15] =
                        (O[nq][dt][r] + obw[(nq * 16 + quad * 4 + r) * 64 + dt * 16 + l15]) * invr;
            }
        }
    }
}

// ---------------------------------------------------------------------------
extern "C" void kernel_launch(void* const* d_in, const int* in_sizes, int n_in,
                              void* d_out, int out_size, void* d_ws, size_t ws_size,
                              hipStream_t stream)
{
    const float* X    = (const float*)d_in[0];
    const float* mask = (const float*)d_in[1];
    const float* Wq   = (const float*)d_in[2];
    const float* bq   = (const float*)d_in[3];
    const float* Wk   = (const float*)d_in[4];
    const float* bk   = (const float*)d_in[5];
    const float* Wv   = (const float*)d_in[6];
    const float* bv   = (const float*)d_in[7];
    float* out = (float*)d_out;

    char* ws = (char*)d_ws;
    u16* Xb = (u16*)(ws);
    u16* Wt = (u16*)(ws + ((size_t)8  << 20));
    u16* Qb = (u16*)(ws + ((size_t)14 << 20));
    u16* Kb = (u16*)(ws + ((size_t)22 << 20));
    u16* Vt = (u16*)(ws + ((size_t)30 << 20));

    convert_x<<<CM * CD / (256 * 8), 256, 0, stream>>>(X, Xb);
    convert_wt<<<dim3(16, 16, 3), 256, 0, stream>>>(Wq, Wk, Wv, Wt);
    qkv_gemm_mfma<<<dim3(CM / 128, CD / 128, 3), 256, 0, stream>>>(
        Xb, Wt, bq, bk, bv, Qb, Kb, Vt);
    attn_mfma<<<dim3(CS / 128, CB * CH), 512, 0, stream>>>(Qb, Kb, Vt, mask, out);
}